// Round 6
// baseline (344.021 us; speedup 1.0000x reference)
//
#include <hip/hip_runtime.h>
#include <hip/hip_bf16.h>

#define BB 32
#define TT 256
#define MM 16
#define DD 128
#define HH 128

typedef unsigned int uint;
typedef unsigned short ushort;
typedef float v2f __attribute__((ext_vector_type(2)));

__device__ __forceinline__ float bl16(uint u){ return __uint_as_float(u << 16); }
__device__ __forceinline__ float bh16(uint u){ return __uint_as_float(u & 0xffff0000u); }

__device__ __forceinline__ ushort f2bu(float f){
  __hip_bfloat16 h = __float2bfloat16(f);
  return *(ushort*)&h;
}

__device__ __forceinline__ float hsig(float x){
  return fminf(fmaxf(fmaf(x, 0.2f, 0.5f), 0.0f), 1.0f);
}
__device__ __forceinline__ float tanh_f(float x){
  return 1.0f - 2.0f / (__expf(2.0f * x) + 1.0f);   // saturates correctly
}

__device__ __forceinline__ v2f fma2(v2f a, v2f b, v2f c){
#if __has_builtin(__builtin_elementwise_fma)
  return __builtin_elementwise_fma(a, b, c);        // -> v_pk_fma_f32
#else
  v2f r; r.x = fmaf(a.x, b.x, c.x); r.y = fmaf(a.y, b.y, c.y); return r;
#endif
}

// ---------------- K_init: dtype probe (flag=1 bf16, 0 fp32) + v_x[d] = sum_h W_a[d,h]
__global__ __launch_bounds__(128) void k_init(const void* __restrict__ xraw,
                                              const void* __restrict__ Wa,
                                              int* __restrict__ flag,
                                              float* __restrict__ vx){
  __shared__ int cnt[128];
  __shared__ int smode;
  int tid = threadIdx.x;
  const ushort* u = (const ushort*)xraw;
  int c = 0;
  for (int j = 0; j < 16; ++j){
    ushort v = u[2 * (tid * 16 + j)];
    float f = __uint_as_float(((uint)v) << 16);
    if (f == f && fabsf(f) < 64.f && fabsf(f) > 1e-12f) ++c;
  }
  cnt[tid] = c;
  __syncthreads();
  if (tid == 0){
    int s = 0;
    for (int j = 0; j < 128; ++j) s += cnt[j];
    int m = (s > 1024) ? 1 : 0;
    smode = m; *flag = m;
  }
  __syncthreads();
  int mode = smode;

  int d = tid;
  float s = 0.f;
  if (mode){
    const uint4* row = (const uint4*)((const ushort*)Wa + d * HH);
    #pragma unroll
    for (int q = 0; q < 16; ++q){
      uint4 v = row[q];
      s += bl16(v.x) + bh16(v.x) + bl16(v.y) + bh16(v.y)
         + bl16(v.z) + bh16(v.z) + bl16(v.w) + bh16(v.w);
    }
  } else {
    const float4* row = (const float4*)((const float*)Wa + d * HH);
    #pragma unroll
    for (int q = 0; q < 32; ++q){
      float4 v = row[q];
      s += v.x + v.y + v.z + v.w;
    }
  }
  vx[d] = s;
}

// ---------------- K1: per (b,t): softmax over m of x_t·v_x, pool -> new_x (bf16) ----
__global__ __launch_bounds__(128) void k_pool(const void* __restrict__ xraw,
                                              const int* __restrict__ flag,
                                              const float* __restrict__ vx,
                                              __hip_bfloat16* __restrict__ newx){
  __shared__ float xs[MM][DD];     // 8 KB, fp32
  __shared__ float vxs[DD];
  __shared__ float part[128];
  __shared__ float sc[MM];
  int mode = *flag;
  int tid = threadIdx.x;
  int b = blockIdx.x >> 8, t = blockIdx.x & 255;

  float* xdst = &xs[0][0];         // 2048 floats
  if (mode){
    const uint4* s = (const uint4*)((const ushort*)xraw + (size_t)blockIdx.x * 2048);
    #pragma unroll
    for (int q = 0; q < 2; ++q){
      int ch = tid + 128 * q;
      uint4 v = s[ch];
      float* d = &xdst[ch * 8];
      d[0] = bl16(v.x); d[1] = bh16(v.x);
      d[2] = bl16(v.y); d[3] = bh16(v.y);
      d[4] = bl16(v.z); d[5] = bh16(v.z);
      d[6] = bl16(v.w); d[7] = bh16(v.w);
    }
  } else {
    const float4* s = (const float4*)((const float*)xraw + (size_t)blockIdx.x * 2048);
    #pragma unroll
    for (int q = 0; q < 4; ++q){
      int ch = tid + 128 * q;
      *(float4*)&xdst[ch * 4] = s[ch];
    }
  }
  vxs[tid] = vx[tid];
  __syncthreads();

  int m = tid >> 3, cc = tid & 7;
  float p = 0.f;
  #pragma unroll
  for (int j = 0; j < 16; ++j)
    p = fmaf(xs[m][cc * 16 + j], vxs[cc * 16 + j], p);
  part[tid] = p;
  __syncthreads();
  if (tid < MM){
    float s = 0.f;
    #pragma unroll
    for (int q = 0; q < 8; ++q) s += part[tid * 8 + q];
    sc[tid] = s;
  }
  __syncthreads();

  float mx = sc[0];
  #pragma unroll
  for (int m2 = 1; m2 < MM; ++m2) mx = fmaxf(mx, sc[m2]);
  float wgt[MM]; float den = 0.f;
  #pragma unroll
  for (int m2 = 0; m2 < MM; ++m2){ wgt[m2] = __expf(sc[m2] - mx); den += wgt[m2]; }
  float inv = 1.0f / den;

  float acc = 0.f;
  #pragma unroll
  for (int m2 = 0; m2 < MM; ++m2)
    acc = fmaf(wgt[m2], xs[m2][tid], acc);
  newx[((size_t)t * BB + b) * DD + tid] = __float2bfloat16(acc * inv);
}

// ---------------- K2: Xp[r, g*128+j] = b_g[j] + sum_d new_x[r,d] * W_g[d,j] ---------
__global__ __launch_bounds__(256) void k_xproj(const __hip_bfloat16* __restrict__ nx,
  const void* __restrict__ W0, const void* __restrict__ W1,
  const void* __restrict__ W2, const void* __restrict__ W3,
  const void* __restrict__ b0_, const void* __restrict__ b1_,
  const void* __restrict__ b2_, const void* __restrict__ b3_,
  const int* __restrict__ flag, float* __restrict__ Xp)
{
  __shared__ __hip_bfloat16 As[128][DD];  // 32 KB
  __shared__ __hip_bfloat16 Ws[DD][HH];   // 32 KB
  int mode = *flag;
  int tid = threadIdx.x;
  int r0 = blockIdx.x * 128;
  int g  = blockIdx.y;
  const void* W  = (g == 0) ? W0  : (g == 1) ? W1  : (g == 2) ? W2  : W3;
  const void* bb = (g == 0) ? b0_ : (g == 1) ? b1_ : (g == 2) ? b2_ : b3_;

  const uint4* asrc = (const uint4*)(nx + (size_t)r0 * DD);
  uint4* adst = (uint4*)&As[0][0];
  uint4* wdst = (uint4*)&Ws[0][0];
  #pragma unroll
  for (int q = 0; q < 8; ++q) adst[q * 256 + tid] = asrc[q * 256 + tid];

  if (mode){
    const uint4* wsrc = (const uint4*)W;
    #pragma unroll
    for (int q = 0; q < 8; ++q) wdst[q * 256 + tid] = wsrc[q * 256 + tid];
  } else {
    const float4* wsrc = (const float4*)W;
    #pragma unroll
    for (int q = 0; q < 8; ++q){
      int ch = q * 256 + tid;
      float4 a = wsrc[2 * ch], b = wsrc[2 * ch + 1];
      uint4 o;
      o.x = (uint)f2bu(a.x) | ((uint)f2bu(a.y) << 16);
      o.y = (uint)f2bu(a.z) | ((uint)f2bu(a.w) << 16);
      o.z = (uint)f2bu(b.x) | ((uint)f2bu(b.y) << 16);
      o.w = (uint)f2bu(b.z) | ((uint)f2bu(b.w) << 16);
      wdst[ch] = o;
    }
  }
  __syncthreads();

  int ti = tid >> 4, tj = tid & 15;
  int i0 = ti * 8, j0 = tj * 8;
  float acc[8][8] = {};

  for (int k = 0; k < DD; k += 8){
    float a[8][8];
    #pragma unroll
    for (int ii = 0; ii < 8; ++ii){
      uint4 v = *(const uint4*)&As[i0 + ii][k];
      a[ii][0] = bl16(v.x); a[ii][1] = bh16(v.x);
      a[ii][2] = bl16(v.y); a[ii][3] = bh16(v.y);
      a[ii][4] = bl16(v.z); a[ii][5] = bh16(v.z);
      a[ii][6] = bl16(v.w); a[ii][7] = bh16(v.w);
    }
    #pragma unroll
    for (int kk = 0; kk < 8; ++kk){
      uint4 v = *(const uint4*)&Ws[k + kk][j0];
      float w[8];
      w[0] = bl16(v.x); w[1] = bh16(v.x);
      w[2] = bl16(v.y); w[3] = bh16(v.y);
      w[4] = bl16(v.z); w[5] = bh16(v.z);
      w[6] = bl16(v.w); w[7] = bh16(v.w);
      #pragma unroll
      for (int ii = 0; ii < 8; ++ii)
        #pragma unroll
        for (int jj = 0; jj < 8; ++jj)
          acc[ii][jj] = fmaf(a[ii][kk], w[jj], acc[ii][jj]);
    }
  }

  float bias[8];
  if (mode){
    #pragma unroll
    for (int jj = 0; jj < 8; ++jj)
      bias[jj] = __uint_as_float(((uint)((const ushort*)bb)[j0 + jj]) << 16);
  } else {
    #pragma unroll
    for (int jj = 0; jj < 8; ++jj) bias[jj] = ((const float*)bb)[j0 + jj];
  }
  #pragma unroll
  for (int ii = 0; ii < 8; ++ii){
    size_t r = (size_t)(r0 + i0 + ii);
    float* orow = &Xp[r * 512 + g * HH + j0];
    float4 o1 = make_float4(acc[ii][0] + bias[0], acc[ii][1] + bias[1],
                            acc[ii][2] + bias[2], acc[ii][3] + bias[3]);
    float4 o2 = make_float4(acc[ii][4] + bias[4], acc[ii][5] + bias[5],
                            acc[ii][6] + bias[6], acc[ii][7] + bias[7]);
    *(float4*)orow       = o1;
    *(float4*)(orow + 4) = o2;
  }
}

// ---------------- K3: recurrence, full-k per thread, quad-interleaved gates ---------
// thread tid: col j = tid>>2 (0..127), gate g = tid&3. U column (128 fp32) in regs.
// Matvec: h broadcast from LDS (uniform-addr ds_read_b128), k-pairs via v_pk_fma_f32.
// Gate exchange: the 4 gates of col j are the 4 lanes of a quad -> v_mov_dpp
// quad_perm broadcasts (no LDS); all 4 lanes redundantly compute identical c/h.
// h double-buffered in LDS -> ONE barrier per step.
__global__ __launch_bounds__(512, 2) void k_rec(const float* __restrict__ Xp,
  const void* __restrict__ Ui, const void* __restrict__ Uf,
  const void* __restrict__ Uc, const void* __restrict__ Uo,
  const int* __restrict__ flag, float* __restrict__ out)
{
  __shared__ __align__(16) float hlds[2][HH];   // 1 KB
  int mode = *flag;
  int tid = threadIdx.x;
  int b   = blockIdx.x;
  int j   = tid >> 2;                 // output col 0..127
  int g   = tid & 3;                  // gate i/f/c/o
  const void* Ug = (g == 0) ? Ui : (g == 1) ? Uf : (g == 2) ? Uc : Uo;

  // U column j as 64 k-pairs in registers
  v2f U2[64];
  if (mode){
    const ushort* U16 = (const ushort*)Ug;
    #pragma unroll
    for (int q = 0; q < 64; ++q){
      v2f u; u.x = bl16((uint)U16[(size_t)(2 * q) * HH + j] << 16 >> 16);  // placeholder
      // (correct conversion below)
      u.x = __uint_as_float(((uint)U16[(size_t)(2 * q) * HH + j]) << 16);
      u.y = __uint_as_float(((uint)U16[(size_t)(2 * q + 1) * HH + j]) << 16);
      U2[q] = u;
    }
  } else {
    const float* U32 = (const float*)Ug;
    #pragma unroll
    for (int q = 0; q < 64; ++q){
      v2f u; u.x = U32[(size_t)(2 * q) * HH + j];
      u.y = U32[(size_t)(2 * q + 1) * HH + j];
      U2[q] = u;
    }
  }

  if (tid < HH) hlds[0][tid] = 0.f;
  float cst = 0.f, vh = 0.f;
  const float* xb = Xp + (size_t)b * 512 + g * HH + j;   // step stride 32*512=16384
  float xp = xb[0];
  __syncthreads();

  for (int t = 0; t < TT; ++t){
    // prefetch next step's x-presum (hidden behind matvec)
    int tn = (t + 1 < TT) ? t + 1 : t;
    float xpn = xb[(size_t)tn * 16384];

    // matvec: acc = sum_k h[k] * U[k][j]   (h via LDS broadcast reads)
    const float4* hb4 = (const float4*)&hlds[t & 1][0];
    v2f a0 = {0.f, 0.f}, a1 = {0.f, 0.f};
    #pragma unroll
    for (int kk = 0; kk < 32; ++kk){
      float4 h4 = hb4[kk];
      v2f hA; hA.x = h4.x; hA.y = h4.y;
      v2f hB; hB.x = h4.z; hB.y = h4.w;
      a0 = fma2(hA, U2[2 * kk],     a0);
      a1 = fma2(hB, U2[2 * kk + 1], a1);
    }
    float p = a0.x + a0.y + a1.x + a1.y + xp;

    // quad gate exchange: slot s of each quad holds gate s's presum
    int pI = __builtin_amdgcn_mov_dpp(__float_as_int(p), 0x00, 0xf, 0xf, true);
    int pF = __builtin_amdgcn_mov_dpp(__float_as_int(p), 0x55, 0xf, 0xf, true);
    int pC = __builtin_amdgcn_mov_dpp(__float_as_int(p), 0xAA, 0xf, 0xf, true);
    int pO = __builtin_amdgcn_mov_dpp(__float_as_int(p), 0xFF, 0xf, 0xf, true);
    float ig = hsig(__int_as_float(pI));
    float fg = hsig(__int_as_float(pF));
    float og = hsig(__int_as_float(pO));
    float gg = tanh_f(__int_as_float(pC));
    cst = fmaf(fg, cst, ig * gg);
    vh  = og * tanh_f(cst);

    if (g == 0) hlds[(t + 1) & 1][j] = vh;
    xp = xpn;
    __syncthreads();
  }

  if (g == 0) out[b * HH + j] = vh;
}

extern "C" void kernel_launch(void* const* d_in, const int* in_sizes, int n_in,
                              void* d_out, int out_size, void* d_ws, size_t ws_size,
                              hipStream_t stream) {
  (void)in_sizes; (void)n_in; (void)out_size; (void)ws_size;

  // ---- workspace layout (~18.9 MB) ----
  char* ws = (char*)d_ws;
  int* flag = (int*)ws;
  float* vx = (float*)(ws + 16);
  __hip_bfloat16* newx = (__hip_bfloat16*)(ws + 1024);
  float* Xp = (float*)(ws + 1024 + (size_t)2 * 1024 * 1024);

  k_init<<<1, 128, 0, stream>>>(d_in[0], d_in[1], flag, vx);
  k_pool<<<BB * TT, 128, 0, stream>>>(d_in[0], flag, vx, newx);
  dim3 g2(64, 4);
  k_xproj<<<g2, 256, 0, stream>>>(newx,
      d_in[3], d_in[6], d_in[9], d_in[12],     // W_i, W_f, W_c, W_o
      d_in[5], d_in[8], d_in[11], d_in[14],    // b_i, b_f, b_c, b_o
      flag, Xp);
  k_rec<<<BB, 512, 0, stream>>>(Xp,
      d_in[4], d_in[7], d_in[10], d_in[13],    // U_i, U_f, U_c, U_o
      flag, (float*)d_out);
}

// Round 7
// 309.865 us; speedup vs baseline: 1.1102x; 1.1102x over previous
//
#include <hip/hip_runtime.h>
#include <hip/hip_bf16.h>

#define BB 32
#define TT 256
#define MM 16
#define DD 128
#define HH 128

typedef unsigned int uint;
typedef unsigned short ushort;
typedef float v2f __attribute__((ext_vector_type(2)));

__device__ __forceinline__ float bl16(uint u){ return __uint_as_float(u << 16); }
__device__ __forceinline__ float bh16(uint u){ return __uint_as_float(u & 0xffff0000u); }

__device__ __forceinline__ ushort f2bu(float f){
  __hip_bfloat16 h = __float2bfloat16(f);
  return *(ushort*)&h;
}

__device__ __forceinline__ float hsig(float x){
  return fminf(fmaxf(fmaf(x, 0.2f, 0.5f), 0.0f), 1.0f);
}
__device__ __forceinline__ float tanh_f(float x){
  return 1.0f - 2.0f / (__expf(2.0f * x) + 1.0f);   // saturates correctly
}

__device__ __forceinline__ v2f fma2(v2f a, v2f b, v2f c){
#if __has_builtin(__builtin_elementwise_fma)
  return __builtin_elementwise_fma(a, b, c);        // -> v_pk_fma_f32
#else
  v2f r; r.x = fmaf(a.x, b.x, c.x); r.y = fmaf(a.y, b.y, c.y); return r;
#endif
}

// quad_perm butterfly helpers (within lane quads)
__device__ __forceinline__ float qsum4(float v){
  // v += swap-within-pairs; v += swap-pairs  -> all 4 quad lanes hold the quad sum
  float t1 = __int_as_float(__builtin_amdgcn_mov_dpp(__float_as_int(v), 0xB1, 0xf, 0xf, true)); // [1,0,3,2]
  v += t1;
  float t2 = __int_as_float(__builtin_amdgcn_mov_dpp(__float_as_int(v), 0x4E, 0xf, 0xf, true)); // [2,3,0,1]
  return v + t2;
}

// ---------------- K_init: dtype probe (flag=1 bf16, 0 fp32) + v_x[d] = sum_h W_a[d,h]
__global__ __launch_bounds__(128) void k_init(const void* __restrict__ xraw,
                                              const void* __restrict__ Wa,
                                              int* __restrict__ flag,
                                              float* __restrict__ vx){
  __shared__ int cnt[128];
  __shared__ int smode;
  int tid = threadIdx.x;
  const ushort* u = (const ushort*)xraw;
  int c = 0;
  for (int j = 0; j < 16; ++j){
    ushort v = u[2 * (tid * 16 + j)];
    float f = __uint_as_float(((uint)v) << 16);
    if (f == f && fabsf(f) < 64.f && fabsf(f) > 1e-12f) ++c;
  }
  cnt[tid] = c;
  __syncthreads();
  if (tid == 0){
    int s = 0;
    for (int j = 0; j < 128; ++j) s += cnt[j];
    int m = (s > 1024) ? 1 : 0;
    smode = m; *flag = m;
  }
  __syncthreads();
  int mode = smode;

  int d = tid;
  float s = 0.f;
  if (mode){
    const uint4* row = (const uint4*)((const ushort*)Wa + d * HH);
    #pragma unroll
    for (int q = 0; q < 16; ++q){
      uint4 v = row[q];
      s += bl16(v.x) + bh16(v.x) + bl16(v.y) + bh16(v.y)
         + bl16(v.z) + bh16(v.z) + bl16(v.w) + bh16(v.w);
    }
  } else {
    const float4* row = (const float4*)((const float*)Wa + d * HH);
    #pragma unroll
    for (int q = 0; q < 32; ++q){
      float4 v = row[q];
      s += v.x + v.y + v.z + v.w;
    }
  }
  vx[d] = s;
}

// ---------------- K1: per (b,t): softmax over m of x_t·v_x, pool -> new_x (bf16) ----
__global__ __launch_bounds__(128) void k_pool(const void* __restrict__ xraw,
                                              const int* __restrict__ flag,
                                              const float* __restrict__ vx,
                                              __hip_bfloat16* __restrict__ newx){
  __shared__ float xs[MM][DD];     // 8 KB, fp32
  __shared__ float vxs[DD];
  __shared__ float part[128];
  __shared__ float sc[MM];
  int mode = *flag;
  int tid = threadIdx.x;
  int b = blockIdx.x >> 8, t = blockIdx.x & 255;

  float* xdst = &xs[0][0];         // 2048 floats
  if (mode){
    const uint4* s = (const uint4*)((const ushort*)xraw + (size_t)blockIdx.x * 2048);
    #pragma unroll
    for (int q = 0; q < 2; ++q){
      int ch = tid + 128 * q;
      uint4 v = s[ch];
      float* d = &xdst[ch * 8];
      d[0] = bl16(v.x); d[1] = bh16(v.x);
      d[2] = bl16(v.y); d[3] = bh16(v.y);
      d[4] = bl16(v.z); d[5] = bh16(v.z);
      d[6] = bl16(v.w); d[7] = bh16(v.w);
    }
  } else {
    const float4* s = (const float4*)((const float*)xraw + (size_t)blockIdx.x * 2048);
    #pragma unroll
    for (int q = 0; q < 4; ++q){
      int ch = tid + 128 * q;
      *(float4*)&xdst[ch * 4] = s[ch];
    }
  }
  vxs[tid] = vx[tid];
  __syncthreads();

  int m = tid >> 3, cc = tid & 7;
  float p = 0.f;
  #pragma unroll
  for (int j = 0; j < 16; ++j)
    p = fmaf(xs[m][cc * 16 + j], vxs[cc * 16 + j], p);
  part[tid] = p;
  __syncthreads();
  if (tid < MM){
    float s = 0.f;
    #pragma unroll
    for (int q = 0; q < 8; ++q) s += part[tid * 8 + q];
    sc[tid] = s;
  }
  __syncthreads();

  float mx = sc[0];
  #pragma unroll
  for (int m2 = 1; m2 < MM; ++m2) mx = fmaxf(mx, sc[m2]);
  float wgt[MM]; float den = 0.f;
  #pragma unroll
  for (int m2 = 0; m2 < MM; ++m2){ wgt[m2] = __expf(sc[m2] - mx); den += wgt[m2]; }
  float inv = 1.0f / den;

  float acc = 0.f;
  #pragma unroll
  for (int m2 = 0; m2 < MM; ++m2)
    acc = fmaf(wgt[m2], xs[m2][tid], acc);
  newx[((size_t)t * BB + b) * DD + tid] = __float2bfloat16(acc * inv);
}

// ---------------- K2: Xp[r, g*128+j] = b_g[j] + sum_d new_x[r,d] * W_g[d,j] ---------
__global__ __launch_bounds__(256) void k_xproj(const __hip_bfloat16* __restrict__ nx,
  const void* __restrict__ W0, const void* __restrict__ W1,
  const void* __restrict__ W2, const void* __restrict__ W3,
  const void* __restrict__ b0_, const void* __restrict__ b1_,
  const void* __restrict__ b2_, const void* __restrict__ b3_,
  const int* __restrict__ flag, float* __restrict__ Xp)
{
  __shared__ __hip_bfloat16 As[128][DD];  // 32 KB
  __shared__ __hip_bfloat16 Ws[DD][HH];   // 32 KB
  int mode = *flag;
  int tid = threadIdx.x;
  int r0 = blockIdx.x * 128;
  int g  = blockIdx.y;
  const void* W  = (g == 0) ? W0  : (g == 1) ? W1  : (g == 2) ? W2  : W3;
  const void* bb = (g == 0) ? b0_ : (g == 1) ? b1_ : (g == 2) ? b2_ : b3_;

  const uint4* asrc = (const uint4*)(nx + (size_t)r0 * DD);
  uint4* adst = (uint4*)&As[0][0];
  uint4* wdst = (uint4*)&Ws[0][0];
  #pragma unroll
  for (int q = 0; q < 8; ++q) adst[q * 256 + tid] = asrc[q * 256 + tid];

  if (mode){
    const uint4* wsrc = (const uint4*)W;
    #pragma unroll
    for (int q = 0; q < 8; ++q) wdst[q * 256 + tid] = wsrc[q * 256 + tid];
  } else {
    const float4* wsrc = (const float4*)W;
    #pragma unroll
    for (int q = 0; q < 8; ++q){
      int ch = q * 256 + tid;
      float4 a = wsrc[2 * ch], b = wsrc[2 * ch + 1];
      uint4 o;
      o.x = (uint)f2bu(a.x) | ((uint)f2bu(a.y) << 16);
      o.y = (uint)f2bu(a.z) | ((uint)f2bu(a.w) << 16);
      o.z = (uint)f2bu(b.x) | ((uint)f2bu(b.y) << 16);
      o.w = (uint)f2bu(b.z) | ((uint)f2bu(b.w) << 16);
      wdst[ch] = o;
    }
  }
  __syncthreads();

  int ti = tid >> 4, tj = tid & 15;
  int i0 = ti * 8, j0 = tj * 8;
  float acc[8][8] = {};

  for (int k = 0; k < DD; k += 8){
    float a[8][8];
    #pragma unroll
    for (int ii = 0; ii < 8; ++ii){
      uint4 v = *(const uint4*)&As[i0 + ii][k];
      a[ii][0] = bl16(v.x); a[ii][1] = bh16(v.x);
      a[ii][2] = bl16(v.y); a[ii][3] = bh16(v.y);
      a[ii][4] = bl16(v.z); a[ii][5] = bh16(v.z);
      a[ii][6] = bl16(v.w); a[ii][7] = bh16(v.w);
    }
    #pragma unroll
    for (int kk = 0; kk < 8; ++kk){
      uint4 v = *(const uint4*)&Ws[k + kk][j0];
      float w[8];
      w[0] = bl16(v.x); w[1] = bh16(v.x);
      w[2] = bl16(v.y); w[3] = bh16(v.y);
      w[4] = bl16(v.z); w[5] = bh16(v.z);
      w[6] = bl16(v.w); w[7] = bh16(v.w);
      #pragma unroll
      for (int ii = 0; ii < 8; ++ii)
        #pragma unroll
        for (int jj = 0; jj < 8; ++jj)
          acc[ii][jj] = fmaf(a[ii][kk], w[jj], acc[ii][jj]);
    }
  }

  float bias[8];
  if (mode){
    #pragma unroll
    for (int jj = 0; jj < 8; ++jj)
      bias[jj] = __uint_as_float(((uint)((const ushort*)bb)[j0 + jj]) << 16);
  } else {
    #pragma unroll
    for (int jj = 0; jj < 8; ++jj) bias[jj] = ((const float*)bb)[j0 + jj];
  }
  #pragma unroll
  for (int ii = 0; ii < 8; ++ii){
    size_t r = (size_t)(r0 + i0 + ii);
    float* orow = &Xp[r * 512 + g * HH + j0];
    float4 o1 = make_float4(acc[ii][0] + bias[0], acc[ii][1] + bias[1],
                            acc[ii][2] + bias[2], acc[ii][3] + bias[3]);
    float4 o2 = make_float4(acc[ii][4] + bias[4], acc[ii][5] + bias[5],
                            acc[ii][6] + bias[6], acc[ii][7] + bias[7]);
    *(float4*)orow       = o1;
    *(float4*)(orow + 4) = o2;
  }
}

// ---------------- K3: recurrence. thread = (col j = tid>>2, k-quarter q = tid&3) ----
// Each thread computes ALL 4 gates of col j over its 32-k quarter (64 pk_fma,
// U = 128 VGPRs). h-broadcast: 8 ds_read_b128/thread (4x fewer bytes than R6).
// Quad lanes hold the 4 k-quarters of col j -> 2 DPP butterfly adds per gate give
// every lane all 4 presums; c,h computed redundantly x4 (no exchange, 1 barrier).
// Bank rotation: quad member q reads h float4-slots in order (kk+2q)&7 and its U
// registers are loaded in the same rotated order (conflict-free, static reg idx).
__global__ __launch_bounds__(512, 2) void k_rec(const float* __restrict__ Xp,
  const void* __restrict__ Ui, const void* __restrict__ Uf,
  const void* __restrict__ Uc, const void* __restrict__ Uo,
  const int* __restrict__ flag, float* __restrict__ out)
{
  __shared__ __align__(16) float hlds[2][HH];   // 1 KB
  int mode = *flag;
  int tid = threadIdx.x;
  int b   = blockIdx.x;
  int q   = tid & 3;                  // k-quarter; also "my" gate for the x-add
  int j   = tid >> 2;                 // output col 0..127
  int k0  = q * 32;

  // masks for folding x-presum into exactly one quad lane's partial per gate
  float m0 = (q == 0) ? 1.f : 0.f;
  float m1 = (q == 1) ? 1.f : 0.f;
  float m2 = (q == 2) ? 1.f : 0.f;
  float m3 = (q == 3) ? 1.f : 0.f;

  // U2[g][2*kk4+m]: k-pair at physical float4-slot kr4=(kk4+2q)&7, m-th pair of it
  const void* Ugs[4] = {Ui, Uf, Uc, Uo};
  v2f U2[4][16];
  #pragma unroll
  for (int g = 0; g < 4; ++g){
    #pragma unroll
    for (int kk4 = 0; kk4 < 8; ++kk4){
      int kr4 = (kk4 + 2 * q) & 7;          // rotated slot
      #pragma unroll
      for (int m = 0; m < 2; ++m){
        int kp = k0 + 4 * kr4 + 2 * m;       // physical k of pair start
        v2f u;
        if (mode){
          const ushort* U16 = (const ushort*)Ugs[g];
          u.x = __uint_as_float(((uint)U16[(size_t)kp * HH + j]) << 16);
          u.y = __uint_as_float(((uint)U16[(size_t)(kp + 1) * HH + j]) << 16);
        } else {
          const float* U32 = (const float*)Ugs[g];
          u.x = U32[(size_t)kp * HH + j];
          u.y = U32[(size_t)(kp + 1) * HH + j];
        }
        U2[g][2 * kk4 + m] = u;
      }
    }
  }

  if (tid < HH) hlds[0][tid] = 0.f;
  float cst = 0.f, vh = 0.f;
  const float* xb = Xp + (size_t)b * 512 + q * HH + j;   // step stride = 32*512
  float xp = xb[0];
  __syncthreads();

  for (int t = 0; t < TT; ++t){
    int tn = (t + 1 < TT) ? t + 1 : t;
    float xpn = xb[(size_t)tn * (BB * 512)];             // next-step prefetch

    const float4* hb4 = (const float4*)&hlds[t & 1][k0]; // 8 float4 = my 32 k's
    v2f a0[4] = {{0,0},{0,0},{0,0},{0,0}};
    v2f a1[4] = {{0,0},{0,0},{0,0},{0,0}};
    #pragma unroll
    for (int kk4 = 0; kk4 < 8; ++kk4){
      int kr4 = (kk4 + 2 * q) & 7;                       // rotated (runtime addr ok)
      float4 h4 = hb4[kr4];
      v2f hA; hA.x = h4.x; hA.y = h4.y;
      v2f hB; hB.x = h4.z; hB.y = h4.w;
      #pragma unroll
      for (int g = 0; g < 4; ++g){
        a0[g] = fma2(hA, U2[g][2 * kk4],     a0[g]);
        a1[g] = fma2(hB, U2[g][2 * kk4 + 1], a1[g]);
      }
    }
    v2f s0 = a0[0] + a1[0]; float p0 = s0.x + s0.y;
    v2f s1 = a0[1] + a1[1]; float p1 = s1.x + s1.y;
    v2f s2 = a0[2] + a1[2]; float p2 = s2.x + s2.y;
    v2f s3 = a0[3] + a1[3]; float p3 = s3.x + s3.y;
    // fold x-presums (lane q carries gate q's x value)
    p0 = fmaf(m0, xp, p0);
    p1 = fmaf(m1, xp, p1);
    p2 = fmaf(m2, xp, p2);
    p3 = fmaf(m3, xp, p3);
    // quad butterflies: every lane gets all 4 full presums
    p0 = qsum4(p0); p1 = qsum4(p1); p2 = qsum4(p2); p3 = qsum4(p3);

    float ig = hsig(p0), fg = hsig(p1), og = hsig(p3);
    float gg = tanh_f(p2);
    cst = fmaf(fg, cst, ig * gg);
    vh  = og * tanh_f(cst);

    if (q == 0) hlds[(t + 1) & 1][j] = vh;
    xp = xpn;
    __syncthreads();
  }

  if (q == 0) out[b * HH + j] = vh;
}

extern "C" void kernel_launch(void* const* d_in, const int* in_sizes, int n_in,
                              void* d_out, int out_size, void* d_ws, size_t ws_size,
                              hipStream_t stream) {
  (void)in_sizes; (void)n_in; (void)out_size; (void)ws_size;

  // ---- workspace layout (~18.9 MB) ----
  char* ws = (char*)d_ws;
  int* flag = (int*)ws;
  float* vx = (float*)(ws + 16);
  __hip_bfloat16* newx = (__hip_bfloat16*)(ws + 1024);
  float* Xp = (float*)(ws + 1024 + (size_t)2 * 1024 * 1024);

  k_init<<<1, 128, 0, stream>>>(d_in[0], d_in[1], flag, vx);
  k_pool<<<BB * TT, 128, 0, stream>>>(d_in[0], flag, vx, newx);
  dim3 g2(64, 4);
  k_xproj<<<g2, 256, 0, stream>>>(newx,
      d_in[3], d_in[6], d_in[9], d_in[12],     // W_i, W_f, W_c, W_o
      d_in[5], d_in[8], d_in[11], d_in[14],    // b_i, b_f, b_c, b_o
      flag, Xp);
  k_rec<<<BB, 512, 0, stream>>>(Xp,
      d_in[4], d_in[7], d_in[10], d_in[13],    // U_i, U_f, U_c, U_o
      flag, (float*)d_out);
}